// Round 1
// 8009.668 us; speedup vs baseline: 1.1461x; 1.1461x over previous
//
#include <hip/hip_runtime.h>
#include <hip/hip_bf16.h>
#include <stdint.h>

#define TB 32      // batch
#define TT 1024    // time steps
#define TN 512     // hidden

typedef __attribute__((ext_vector_type(8))) short short8;
typedef __attribute__((ext_vector_type(4))) float f32x4;
typedef __attribute__((ext_vector_type(4))) short short4v;
typedef unsigned long long ull;

static __device__ inline unsigned short f2bf(float f) {
  union { __hip_bfloat16 h; unsigned short u; } c;
  c.h = __float2bfloat16(f);
  return c.u;
}

static __device__ inline short8 pack_bf8(const float* __restrict__ p) {
  float4 a = *(const float4*)p;
  float4 b = *(const float4*)(p + 4);
  short8 o;
  o[0] = (short)f2bf(a.x); o[1] = (short)f2bf(a.y);
  o[2] = (short)f2bf(a.z); o[3] = (short)f2bf(a.w);
  o[4] = (short)f2bf(b.x); o[5] = (short)f2bf(b.y);
  o[6] = (short)f2bf(b.z); o[7] = (short)f2bf(b.w);
  return o;
}

// Coherent 16B load bypassing L1/L2 (sc0 sc1): reads the device coherence
// point. Inline asm so the backend cannot insert per-load waits (the 8B
// __hip_atomic_load chain was the suspected ~9us/step serialization pole).
#define HLOAD(dst, base, imm)                                              \
  asm volatile("global_load_dwordx4 %0, %1, off offset:" #imm " sc0 sc1"   \
               : "=v"(dst) : "v"(base) : "memory")

// ---------------- prep: zero h patch buffers & flag words (ws is 0xAA-poisoned) ----
__global__ void prep_kernel(short4v* __restrict__ hbuf, unsigned* __restrict__ flags) {
  const int i = blockIdx.x * 256 + threadIdx.x;
  if (i < (2 * 2 * TB * TN / 4)) {  // 16384 x 8B = 131072 B of patches
    short4v z; z.x = 0; z.y = 0; z.z = 0; z.w = 0;
    hbuf[i] = z;
  }
  if (i < 128) flags[i] = 0u;
}

// ---------------- persistent bidirectional GRU recurrence ----------------
// grid: 32 blocks (dir = blk>>4, slice j = blk&15), 256 threads (4 waves).
// wave w: mt = w&1 (batch rows mt*16..+15), nt = w>>1 (cols nt*16..+15 of slice).
//
// h exchange redesign vs previous round:
//  * hp layout: [dir][mt][buf][patch p=j*2+nt][512B], each patch a contiguous
//    row-major [16 rows][16 cols] bf16 tile in MFMA-A-fragment-ready order.
//  * producer: in-wave transpose (16 shfl) -> ONE 8B-per-lane coherent store
//    publishes the whole patch as 4 full 128B lines (no partial-sector RMW).
//  * consumer: 16 asm global_load_dwordx4 sc0 sc1 (contiguous, pipelined),
//    single vmcnt(0) + sched_barrier before the MFMAs.
//  * flags: ONE word per block (16/dir, one line/dir) published after the
//    per-step __syncthreads (whose implicit vmcnt(0) drains the patch store);
//    only lanes 0..15 poll -> poll traffic /4.
__global__ __launch_bounds__(256, 1) void gru_kernel(
    const float* __restrict__ x,            // [B][T][N] fp32
    const float* __restrict__ wihF, const float* __restrict__ whhF,
    const float* __restrict__ wihB, const float* __restrict__ whhB,
    const float* __restrict__ bihF, const float* __restrict__ bhhF,
    const float* __restrict__ bihB, const float* __restrict__ bhhB,
    unsigned short* __restrict__ hbuf,      // 131072 B of h patches
    unsigned* __restrict__ flags,           // [2 dirs][32] u32 (16 used/dir)
    float* __restrict__ out)                // [B][T][2N] fp32
{
  const int wg   = blockIdx.x;
  const int dir  = wg >> 4;
  const int j    = wg & 15;
  const int tid  = threadIdx.x;
  const int lane = tid & 63;
  const int w    = tid >> 6;
  const int mt   = w & 1;
  const int nt   = w >> 1;
  const int l15  = lane & 15;
  const int l4   = lane >> 4;                 // 0..3
  const int coln = j * 32 + nt * 16 + l15;    // global hidden col 0..511
  const int brow = mt * 16 + l15;             // batch row for A-frags

  const float* wih = dir ? wihB : wihF;
  const float* whh = dir ? whhB : whhF;
  const float* bih = dir ? bihB : bihF;
  const float* bhh = dir ? bhhB : bhhF;

  unsigned char* hp = (unsigned char*)hbuf;
  unsigned* flg = flags + dir * 32;           // this dir's 16 block-flags (1 line)
  const int grp = dir * 2 + mt;               // recurrence group 0..3
  const int p   = j * 2 + nt;                 // this wave's patch slot 0..31

  // Wih r,z gate fragments in LDS, fragment-ordered (conflict-free ds_read_b128). 64KB.
  __shared__ unsigned short wih_lds[2][2][16][512];

  // ---- one-time: convert weights fp32 -> bf16 fragments ----
  short8 bwhh[3][16];
#pragma unroll
  for (int g = 0; g < 3; ++g)
#pragma unroll
    for (int ks = 0; ks < 16; ++ks)
      bwhh[g][ks] = pack_bf8(whh + (size_t)(g * TN + coln) * TN + ks * 32 + l4 * 8);

  short8 bwih_n[16];
#pragma unroll
  for (int ks = 0; ks < 16; ++ks)
    bwih_n[ks] = pack_bf8(wih + (size_t)(2 * TN + coln) * TN + ks * 32 + l4 * 8);

  if (mt == 0) {
#pragma unroll
    for (int g = 0; g < 2; ++g)
#pragma unroll
      for (int ks = 0; ks < 16; ++ks) {
        short8 f = pack_bf8(wih + (size_t)(g * TN + coln) * TN + ks * 32 + l4 * 8);
        *(short8*)&wih_lds[nt][g][ks][lane * 8] = f;
      }
  }

  const float bias_r  = bih[coln] + bhh[coln];
  const float bias_z  = bih[TN + coln] + bhh[TN + coln];
  const float bias_in = bih[2 * TN + coln];
  const float bias_hn = bhh[2 * TN + coln];

  // fp32 recurrent state for this wave's own 4 (row,col) patch entries.
  float hstate[4] = {0.f, 0.f, 0.f, 0.f};
  int dead = 0;  // set if a wait ever times out (prevents container-killing hang)

  __syncthreads();  // wih_lds ready

  const int bpat = mt * 16 + l4 * 4;

  for (int t = 0; t < TT; ++t) {
    const int st = dir ? (TT - 1 - t) : t;   // source time index into x

    f32x4 acc_r  = {bias_r,  bias_r,  bias_r,  bias_r};
    f32x4 acc_z  = {bias_z,  bias_z,  bias_z,  bias_z};
    f32x4 acc_in = {bias_in, bias_in, bias_in, bias_in};
    f32x4 acc_hn = {bias_hn, bias_hn, bias_hn, bias_hn};

    // ---- gi = x_t @ Wih^T (barrier-independent: overlaps the wait) ----
    const float* xr = x + (size_t)brow * (TT * TN) + (size_t)st * TN + l4 * 8;
    short8 af[16];
#pragma unroll
    for (int ks = 0; ks < 16; ++ks) af[ks] = pack_bf8(xr + ks * 32);
#pragma unroll
    for (int ks = 0; ks < 16; ++ks) {
      short8 b0 = *(const short8*)&wih_lds[nt][0][ks][lane * 8];
      acc_r = __builtin_amdgcn_mfma_f32_16x16x32_bf16(af[ks], b0, acc_r, 0, 0, 0);
      short8 b1 = *(const short8*)&wih_lds[nt][1][ks][lane * 8];
      acc_z = __builtin_amdgcn_mfma_f32_16x16x32_bf16(af[ks], b1, acc_z, 0, 0, 0);
      acc_in = __builtin_amdgcn_mfma_f32_16x16x32_bf16(af[ks], bwih_n[ks], acc_in, 0, 0, 0);
    }

    // x patch for the output epilogue (fp32, barrier-independent)
    float xv[4];
#pragma unroll
    for (int r = 0; r < 4; ++r)
      xv[r] = x[(size_t)(bpat + r) * (TT * TN) + (size_t)st * TN + coln];

    // ---- warm L2 with next step's x slice (waited only at iter end) ----
    float warm = 0.f;
    if (t + 1 < TT) {
      const int stn = dir ? (TT - 2 - t) : (t + 1);
      const float* wp = x + (size_t)brow * (TT * TN) + (size_t)stn * TN + l4 * 32;
#pragma unroll
      for (int k2 = 0; k2 < 4; ++k2) warm += wp[k2 * 128];  // 64 x 128B lines/instr
    }

    // ---- wait: all 16 same-dir blocks published step t-1 (flag >= t) ----
    if (t > 0 && !dead) {
      const unsigned target = (unsigned)t;
      int spins = 0;
      for (;;) {
        unsigned v = 0xFFFFFFFFu;
        if (lane < 16)
          v = __hip_atomic_load(&flg[lane], __ATOMIC_RELAXED, __HIP_MEMORY_SCOPE_AGENT);
        if (__ballot(v >= target) == ~0ull) break;
        if (++spins > (1 << 22)) { dead = 1; break; }
      }
      asm volatile("" ::: "memory");  // keep h loads below the poll
    }

    // ---- gh = h_{t-1} @ Whh^T: 16 coherent 16B loads from contiguous patches ----
    // A-frag lane l needs rows=l15, hidden cols ks*32+l4*8..+7
    //   -> patch p' = ks*2 + (l4>>1), bytes l15*32 + (l4&1)*16, 16B.
    const ull gb0 = (ull)(uintptr_t)hp + ((ull)(grp * 2 + ((t + 1) & 1)) << 14)
                  + (ull)((l4 >> 1) * 512 + l15 * 32 + (l4 & 1) * 16);
    const ull gb1 = gb0 + 4096, gb2 = gb0 + 8192, gb3 = gb0 + 12288;
    short8 hf[16];
    HLOAD(hf[0],  gb0, 0); HLOAD(hf[1],  gb0, 1024); HLOAD(hf[2],  gb0, 2048); HLOAD(hf[3],  gb0, 3072);
    HLOAD(hf[4],  gb1, 0); HLOAD(hf[5],  gb1, 1024); HLOAD(hf[6],  gb1, 2048); HLOAD(hf[7],  gb1, 3072);
    HLOAD(hf[8],  gb2, 0); HLOAD(hf[9],  gb2, 1024); HLOAD(hf[10], gb2, 2048); HLOAD(hf[11], gb2, 3072);
    HLOAD(hf[12], gb3, 0); HLOAD(hf[13], gb3, 1024); HLOAD(hf[14], gb3, 2048); HLOAD(hf[15], gb3, 3072);
    asm volatile("s_waitcnt vmcnt(0)" ::: "memory");
    __builtin_amdgcn_sched_barrier(0);   // rule #18: no MFMA hoist past the waitcnt

#pragma unroll
    for (int ks = 0; ks < 16; ++ks) {
      acc_r  = __builtin_amdgcn_mfma_f32_16x16x32_bf16(hf[ks], bwhh[0][ks], acc_r, 0, 0, 0);
      acc_z  = __builtin_amdgcn_mfma_f32_16x16x32_bf16(hf[ks], bwhh[1][ks], acc_z, 0, 0, 0);
      acc_hn = __builtin_amdgcn_mfma_f32_16x16x32_bf16(hf[ks], bwhh[2][ks], acc_hn, 0, 0, 0);
    }

    // ---- gates + state update ----
    float hout[4];
#pragma unroll
    for (int r = 0; r < 4; ++r) {
      float rg = 1.0f / (1.0f + __expf(-acc_r[r]));
      float zg = 1.0f / (1.0f + __expf(-acc_z[r]));
      float e2 = __expf(2.0f * (acc_in[r] + rg * acc_hn[r]));
      float ng = 1.0f - 2.0f / (e2 + 1.0f);
      float hnew = (1.0f - zg) * ng + zg * hstate[r];
      hstate[r] = hnew;
      hout[r] = hnew;
    }

    // ---- in-wave 16x16 transpose: lane d ends up holding patch bytes d*8..+7
    // (row d>>2, cols (d&3)*4..+3 of the row-major [16][16] bf16 tile).
    // source of h[row][col] is lane (row>>2)*16+col, register r=row&3.
    {
      const int src0 = (lane & 48) + (lane & 3) * 4;
      float g0[4], g1[4], g2[4], g3[4];
#pragma unroll
      for (int k = 0; k < 4; ++k) {
        g0[k] = __shfl(hout[0], src0 + k, 64);
        g1[k] = __shfl(hout[1], src0 + k, 64);
        g2[k] = __shfl(hout[2], src0 + k, 64);
        g3[k] = __shfl(hout[3], src0 + k, 64);
      }
      const int rsel = (lane >> 2) & 3;
      float vv[4];
#pragma unroll
      for (int k = 0; k < 4; ++k) {
        float lo = (rsel & 1) ? g1[k] : g0[k];
        float hi = (rsel & 1) ? g3[k] : g2[k];
        vv[k] = (rsel & 2) ? hi : lo;
      }
      unsigned d0 = (unsigned)f2bf(vv[0]) | ((unsigned)f2bf(vv[1]) << 16);
      unsigned d1 = (unsigned)f2bf(vv[2]) | ((unsigned)f2bf(vv[3]) << 16);
      ull pk = (ull)d0 | ((ull)d1 << 32);
      ull* pw = (ull*)(hp + ((size_t)(grp * 2 + (t & 1)) << 14)
                          + (size_t)p * 512 + (size_t)lane * 8);
      __hip_atomic_store(pw, pk, __ATOMIC_RELAXED, __HIP_MEMORY_SCOPE_AGENT);
    }

    // ---- publish step t: drain patch store, block barrier, ONE flag/block ----
    asm volatile("s_waitcnt vmcnt(0)" ::: "memory");
    __syncthreads();   // implicit vmcnt(0) drain for all 4 waves
    if (tid == 0)
      __hip_atomic_store(&flg[j], (unsigned)(t + 1), __ATOMIC_RELAXED,
                         __HIP_MEMORY_SCOPE_AGENT);

    // ---- out stores AFTER the publish (drain during next step's overlap window) ----
#pragma unroll
    for (int r = 0; r < 4; ++r) {
      __builtin_nontemporal_store(hout[r] + xv[r],
          out + (size_t)(bpat + r) * (TT * 2 * TN) + (size_t)t * (2 * TN) + dir * TN + coln);
    }
    asm volatile("" :: "v"(warm));  // keep warm-prefetch loads alive (no DCE)
  }
}

// ---------------- launch ----------------
extern "C" void kernel_launch(void* const* d_in, const int* in_sizes, int n_in,
                              void* d_out, int out_size, void* d_ws, size_t ws_size,
                              hipStream_t stream) {
  const float* x    = (const float*)d_in[0];
  const float* WihF = (const float*)d_in[1];
  const float* WhhF = (const float*)d_in[2];
  const float* bihF = (const float*)d_in[3];
  const float* bhhF = (const float*)d_in[4];
  const float* WihB = (const float*)d_in[5];
  const float* WhhB = (const float*)d_in[6];
  const float* bihB = (const float*)d_in[7];
  const float* bhhB = (const float*)d_in[8];

  // ws layout: h patches (2 dirs * 2 mt * 2 bufs * 32 patches * 512B = 131072 B)
  //          + flags (512 B)
  unsigned short* hbuf = (unsigned short*)d_ws;
  unsigned* flags      = (unsigned*)((char*)d_ws + (size_t)2 * 2 * TB * TN * 2);

  prep_kernel<<<64, 256, 0, stream>>>((short4v*)hbuf, flags);

  gru_kernel<<<32, 256, 0, stream>>>(
      x, WihF, WhhF, WihB, WhhB,
      bihF, bhhF, bihB, bhhB,
      hbuf, flags, (float*)d_out);
}

// Round 4
// 4288.187 us; speedup vs baseline: 2.1408x; 1.8678x over previous
//
#include <hip/hip_runtime.h>
#include <hip/hip_bf16.h>
#include <stdint.h>

#define TB 32      // batch
#define TT 1024    // time steps
#define TN 512     // hidden

typedef __attribute__((ext_vector_type(8))) short short8;
typedef __attribute__((ext_vector_type(4))) float f32x4;
typedef __attribute__((ext_vector_type(4))) short short4v;
typedef unsigned long long ull;

// ws layout:
//   [0,      131072)   h patches (2 dir * 2 mt * 2 buf * 32 patch * 512B)
//   [131072, 131584)   flags
//   [262144, +403MB)   precomputed gi patches (PREGI path only)
#define GI_OFF   262144ull
#define GI_BYTES 402653184ull   // 2*1024*32*2*3*1024 B

static __device__ inline unsigned short f2bf(float f) {
  union { __hip_bfloat16 h; unsigned short u; } c;
  c.h = __float2bfloat16(f);
  return c.u;
}

static __device__ inline short8 pack_bf8(const float* __restrict__ p) {
  float4 a = *(const float4*)p;
  float4 b = *(const float4*)(p + 4);
  short8 o;
  o[0] = (short)f2bf(a.x); o[1] = (short)f2bf(a.y);
  o[2] = (short)f2bf(a.z); o[3] = (short)f2bf(a.w);
  o[4] = (short)f2bf(b.x); o[5] = (short)f2bf(b.y);
  o[6] = (short)f2bf(b.z); o[7] = (short)f2bf(b.w);
  return o;
}

// Coherent 16B load bypassing L1/L2 (sc0 sc1): reads the device coherence point.
#define HLOAD(dst, base, imm)                                              \
  asm volatile("global_load_dwordx4 %0, %1, off offset:" #imm " sc0 sc1"   \
               : "=v"(dst) : "v"(base) : "memory")

// ---------------- prep: zero h patch buffers & flag words (ws is 0xAA-poisoned) ----
__global__ void prep_kernel(short4v* __restrict__ hbuf, unsigned* __restrict__ flags) {
  const int i = blockIdx.x * 256 + threadIdx.x;
  if (i < (2 * 2 * TB * TN / 4)) {
    short4v z; z.x = 0; z.y = 0; z.z = 0; z.w = 0;
    hbuf[i] = z;
  }
  if (i < 128) flags[i] = 0u;
}

// ---------------- phase 1: gi[dir][t] = x_t @ Wih^T + bih, stored patch-wise ----
// grid: 512 blocks = dir(2) x j(16) x tchunk(16), 256 threads (4 waves: mt,nt).
// Runs at full parallelism/clock; removes ALL x reads, pack_bf8 and gi-MFMAs
// from the serial recurrence loop (which runs at DVFS-floor clocks).
// 64KB LDS (r,z gates; n gate in regs). Plain vector stores for gi (the
// nontemporal-vector builtin was the one construct never exercised by a
// passing run on this harness).
// Output layout: [dir][t][p=j*2+nt][mt][g][lane] f32x4 (acc register layout),
// so the recurrence reads its step-t gi as 3 coalesced dwordx4 per lane.
__global__ __launch_bounds__(256) void gi_kernel(
    const float* __restrict__ x,
    const float* __restrict__ wihF, const float* __restrict__ wihB,
    const float* __restrict__ bihF, const float* __restrict__ bihB,
    float* __restrict__ gi)
{
  const int wg   = blockIdx.x;
  const int tc   = wg & 15;
  const int j    = (wg >> 4) & 15;
  const int dir  = wg >> 8;
  const int tid  = threadIdx.x;
  const int lane = tid & 63;
  const int w    = tid >> 6;
  const int mt   = w & 1;
  const int nt   = w >> 1;
  const int l15  = lane & 15;
  const int l4   = lane >> 4;
  const int coln = j * 32 + nt * 16 + l15;
  const int brow = mt * 16 + l15;

  const float* wih = dir ? wihB : wihF;
  const float* bih = dir ? bihB : bihF;

  // r,z gate fragments in LDS (64 KB); n gate in registers.
  __shared__ unsigned short wlds[2][2][16][512];
  short8 bwih_n[16];
#pragma unroll
  for (int ks = 0; ks < 16; ++ks)
    bwih_n[ks] = pack_bf8(wih + (size_t)(2 * TN + coln) * TN + ks * 32 + l4 * 8);

  if (mt == 0) {
#pragma unroll
    for (int g = 0; g < 2; ++g)
#pragma unroll
      for (int ks = 0; ks < 16; ++ks) {
        short8 f = pack_bf8(wih + (size_t)(g * TN + coln) * TN + ks * 32 + l4 * 8);
        *(short8*)&wlds[nt][g][ks][lane * 8] = f;
      }
  }
  const float b0 = bih[coln];
  const float b1 = bih[TN + coln];
  const float b2 = bih[2 * TN + coln];
  __syncthreads();

  for (int tt = 0; tt < 64; ++tt) {
    const int t  = tc * 64 + tt;
    const int st = dir ? (TT - 1 - t) : t;
    const float* xr = x + (size_t)brow * (TT * TN) + (size_t)st * TN + l4 * 8;
    short8 af[16];
#pragma unroll
    for (int ks = 0; ks < 16; ++ks) af[ks] = pack_bf8(xr + ks * 32);

    f32x4 a0 = {b0, b0, b0, b0};
    f32x4 a1 = {b1, b1, b1, b1};
    f32x4 a2 = {b2, b2, b2, b2};
#pragma unroll
    for (int ks = 0; ks < 16; ++ks) {
      short8 f0 = *(const short8*)&wlds[nt][0][ks][lane * 8];
      a0 = __builtin_amdgcn_mfma_f32_16x16x32_bf16(af[ks], f0, a0, 0, 0, 0);
      short8 f1 = *(const short8*)&wlds[nt][1][ks][lane * 8];
      a1 = __builtin_amdgcn_mfma_f32_16x16x32_bf16(af[ks], f1, a1, 0, 0, 0);
      a2 = __builtin_amdgcn_mfma_f32_16x16x32_bf16(af[ks], bwih_n[ks], a2, 0, 0, 0);
    }
    float* gb = gi + ((((size_t)dir * TT + t) * 32 + (j * 2 + nt)) * 2 + mt) * 768
                   + (size_t)lane * 4;
    *(f32x4*)gb         = a0;
    *(f32x4*)(gb + 256) = a1;
    *(f32x4*)(gb + 512) = a2;
  }
}

// ---------------- phase 2: persistent bidirectional GRU recurrence (PREGI) ----
// Serial loop contains ONLY: gi/xv prefetch, poll, 16 coherent h loads,
// 48 hh-MFMAs, gates, transpose, publish. Whh r-gate in regs; z/n gates in
// LDS (64KB) so the kernel sits ~200 VGPRs — r0/r1 were at the 256 cap
// (bwhh+bwih+af >> 256), scratch-spilling weight frags every timestep.
__global__ __launch_bounds__(256, 1) void gru_kernel(
    const float* __restrict__ x,
    const float* __restrict__ whhF, const float* __restrict__ whhB,
    const float* __restrict__ bhhF, const float* __restrict__ bhhB,
    const float* __restrict__ gi,
    unsigned short* __restrict__ hbuf,
    unsigned* __restrict__ flags,
    float* __restrict__ out)
{
  const int wg   = blockIdx.x;
  const int dir  = wg >> 4;
  const int j    = wg & 15;
  const int tid  = threadIdx.x;
  const int lane = tid & 63;
  const int w    = tid >> 6;
  const int mt   = w & 1;
  const int nt   = w >> 1;
  const int l15  = lane & 15;
  const int l4   = lane >> 4;
  const int coln = j * 32 + nt * 16 + l15;

  const float* whh = dir ? whhB : whhF;
  const float* bhh = dir ? bhhB : bhhF;

  unsigned char* hp = (unsigned char*)hbuf;
  unsigned* flg = flags + dir * 32;
  const int grp = dir * 2 + mt;
  const int p   = j * 2 + nt;

  // Whh z,n gate fragments in LDS (shared by both mt waves of a nt). 64KB.
  __shared__ unsigned short whh_lds[2][2][16][512];

  short8 bwhh_r[16];
#pragma unroll
  for (int ks = 0; ks < 16; ++ks)
    bwhh_r[ks] = pack_bf8(whh + (size_t)coln * TN + ks * 32 + l4 * 8);

  if (mt == 0) {
#pragma unroll
    for (int gg = 0; gg < 2; ++gg)
#pragma unroll
      for (int ks = 0; ks < 16; ++ks) {
        short8 f = pack_bf8(whh + (size_t)((gg + 1) * TN + coln) * TN + ks * 32 + l4 * 8);
        *(short8*)&whh_lds[nt][gg][ks][lane * 8] = f;
      }
  }

  const float bhh_r   = bhh[coln];
  const float bhh_z   = bhh[TN + coln];
  const float bias_hn = bhh[2 * TN + coln];

  float hstate[4] = {0.f, 0.f, 0.f, 0.f};
  int dead = 0;

  __syncthreads();  // whh_lds ready

  const int bpat = mt * 16 + l4 * 4;
  // gi base for this wave at t=0; advances 49152 floats (192KB) per step.
  const float* gwave = gi + ((((size_t)dir * TT) * 32 + p) * 2 + mt) * 768
                         + (size_t)lane * 4;

  for (int t = 0; t < TT; ++t) {
    const int st = dir ? (TT - 1 - t) : t;

    // ---- prefetch (plain cached loads, issued before the poll hides them) ----
    const float* gb = gwave + (size_t)t * 49152;
    f32x4 g_r = *(const f32x4*)(gb);
    f32x4 g_z = *(const f32x4*)(gb + 256);
    f32x4 g_n = *(const f32x4*)(gb + 512);
    float xv[4];
#pragma unroll
    for (int r = 0; r < 4; ++r)
      xv[r] = x[(size_t)(bpat + r) * (TT * TN) + (size_t)st * TN + coln];

    // ---- wait: all 16 same-dir blocks published step t-1 (flag >= t) ----
    if (t > 0 && !dead) {
      const unsigned target = (unsigned)t;
      int spins = 0;
      for (;;) {
        unsigned v = 0xFFFFFFFFu;
        if (lane < 16)
          v = __hip_atomic_load(&flg[lane], __ATOMIC_RELAXED, __HIP_MEMORY_SCOPE_AGENT);
        if (__ballot(v >= target) == ~0ull) break;
        if (++spins > (1 << 20)) { dead = 1; break; }
      }
      asm volatile("" ::: "memory");  // keep h loads below the poll
    }

    // ---- gh = h_{t-1} @ Whh^T: 16 coherent 16B loads from contiguous patches ----
    const ull gb0 = (ull)(uintptr_t)hp + ((ull)(grp * 2 + ((t + 1) & 1)) << 14)
                  + (ull)((l4 >> 1) * 512 + l15 * 32 + (l4 & 1) * 16);
    const ull gb1 = gb0 + 4096, gb2 = gb0 + 8192, gb3 = gb0 + 12288;
    short8 hf[16];
    HLOAD(hf[0],  gb0, 0); HLOAD(hf[1],  gb0, 1024); HLOAD(hf[2],  gb0, 2048); HLOAD(hf[3],  gb0, 3072);
    HLOAD(hf[4],  gb1, 0); HLOAD(hf[5],  gb1, 1024); HLOAD(hf[6],  gb1, 2048); HLOAD(hf[7],  gb1, 3072);
    HLOAD(hf[8],  gb2, 0); HLOAD(hf[9],  gb2, 1024); HLOAD(hf[10], gb2, 2048); HLOAD(hf[11], gb2, 3072);
    HLOAD(hf[12], gb3, 0); HLOAD(hf[13], gb3, 1024); HLOAD(hf[14], gb3, 2048); HLOAD(hf[15], gb3, 3072);
    asm volatile("s_waitcnt vmcnt(0)" ::: "memory");
    __builtin_amdgcn_sched_barrier(0);   // rule #18: no MFMA hoist past the waitcnt

    f32x4 acc_r  = g_r + bhh_r;
    f32x4 acc_z  = g_z + bhh_z;
    f32x4 acc_in = g_n;
    f32x4 acc_hn = {bias_hn, bias_hn, bias_hn, bias_hn};

#pragma unroll
    for (int ks = 0; ks < 16; ++ks) {
      acc_r = __builtin_amdgcn_mfma_f32_16x16x32_bf16(hf[ks], bwhh_r[ks], acc_r, 0, 0, 0);
      short8 bz = *(const short8*)&whh_lds[nt][0][ks][lane * 8];
      acc_z = __builtin_amdgcn_mfma_f32_16x16x32_bf16(hf[ks], bz, acc_z, 0, 0, 0);
      short8 bn = *(const short8*)&whh_lds[nt][1][ks][lane * 8];
      acc_hn = __builtin_amdgcn_mfma_f32_16x16x32_bf16(hf[ks], bn, acc_hn, 0, 0, 0);
    }

    // ---- gates + state update ----
    float hout[4];
#pragma unroll
    for (int r = 0; r < 4; ++r) {
      float rg = 1.0f / (1.0f + __expf(-acc_r[r]));
      float zg = 1.0f / (1.0f + __expf(-acc_z[r]));
      float e2 = __expf(2.0f * (acc_in[r] + rg * acc_hn[r]));
      float ng = 1.0f - 2.0f / (e2 + 1.0f);
      float hnew = (1.0f - zg) * ng + zg * hstate[r];
      hstate[r] = hnew;
      hout[r] = hnew;
    }

    // ---- in-wave 16x16 transpose -> ONE 8B-per-lane coherent patch store ----
    {
      const int src0 = (lane & 48) + (lane & 3) * 4;
      float g0[4], g1[4], g2[4], g3[4];
#pragma unroll
      for (int k = 0; k < 4; ++k) {
        g0[k] = __shfl(hout[0], src0 + k, 64);
        g1[k] = __shfl(hout[1], src0 + k, 64);
        g2[k] = __shfl(hout[2], src0 + k, 64);
        g3[k] = __shfl(hout[3], src0 + k, 64);
      }
      const int rsel = (lane >> 2) & 3;
      float vv[4];
#pragma unroll
      for (int k = 0; k < 4; ++k) {
        float lo = (rsel & 1) ? g1[k] : g0[k];
        float hi = (rsel & 1) ? g3[k] : g2[k];
        vv[k] = (rsel & 2) ? hi : lo;
      }
      unsigned d0 = (unsigned)f2bf(vv[0]) | ((unsigned)f2bf(vv[1]) << 16);
      unsigned d1 = (unsigned)f2bf(vv[2]) | ((unsigned)f2bf(vv[3]) << 16);
      ull pk = (ull)d0 | ((ull)d1 << 32);
      ull* pw = (ull*)(hp + ((size_t)(grp * 2 + (t & 1)) << 14)
                          + (size_t)p * 512 + (size_t)lane * 8);
      __hip_atomic_store(pw, pk, __ATOMIC_RELAXED, __HIP_MEMORY_SCOPE_AGENT);
    }

    // ---- publish step t ----
    asm volatile("s_waitcnt vmcnt(0)" ::: "memory");
    __syncthreads();
    if (tid == 0)
      __hip_atomic_store(&flg[j], (unsigned)(t + 1), __ATOMIC_RELAXED,
                         __HIP_MEMORY_SCOPE_AGENT);

    // ---- out stores AFTER the publish ----
#pragma unroll
    for (int r = 0; r < 4; ++r) {
      __builtin_nontemporal_store(hout[r] + xv[r],
          out + (size_t)(bpat + r) * (TT * 2 * TN) + (size_t)t * (2 * TN) + dir * TN + coln);
    }
  }
}

// ---------------- fallback: round-1 kernel verbatim (used if ws too small) ----
__global__ __launch_bounds__(256, 1) void gru_kernel_fb(
    const float* __restrict__ x,
    const float* __restrict__ wihF, const float* __restrict__ whhF,
    const float* __restrict__ wihB, const float* __restrict__ whhB,
    const float* __restrict__ bihF, const float* __restrict__ bhhF,
    const float* __restrict__ bihB, const float* __restrict__ bhhB,
    unsigned short* __restrict__ hbuf,
    unsigned* __restrict__ flags,
    float* __restrict__ out)
{
  const int wg   = blockIdx.x;
  const int dir  = wg >> 4;
  const int j    = wg & 15;
  const int tid  = threadIdx.x;
  const int lane = tid & 63;
  const int w    = tid >> 6;
  const int mt   = w & 1;
  const int nt   = w >> 1;
  const int l15  = lane & 15;
  const int l4   = lane >> 4;
  const int coln = j * 32 + nt * 16 + l15;
  const int brow = mt * 16 + l15;

  const float* wih = dir ? wihB : wihF;
  const float* whh = dir ? whhB : whhF;
  const float* bih = dir ? bihB : bihF;
  const float* bhh = dir ? bhhB : bhhF;

  unsigned char* hp = (unsigned char*)hbuf;
  unsigned* flg = flags + dir * 32;
  const int grp = dir * 2 + mt;
  const int p   = j * 2 + nt;

  __shared__ unsigned short wih_lds[2][2][16][512];

  short8 bwhh[3][16];
#pragma unroll
  for (int g = 0; g < 3; ++g)
#pragma unroll
    for (int ks = 0; ks < 16; ++ks)
      bwhh[g][ks] = pack_bf8(whh + (size_t)(g * TN + coln) * TN + ks * 32 + l4 * 8);

  short8 bwih_n[16];
#pragma unroll
  for (int ks = 0; ks < 16; ++ks)
    bwih_n[ks] = pack_bf8(wih + (size_t)(2 * TN + coln) * TN + ks * 32 + l4 * 8);

  if (mt == 0) {
#pragma unroll
    for (int g = 0; g < 2; ++g)
#pragma unroll
      for (int ks = 0; ks < 16; ++ks) {
        short8 f = pack_bf8(wih + (size_t)(g * TN + coln) * TN + ks * 32 + l4 * 8);
        *(short8*)&wih_lds[nt][g][ks][lane * 8] = f;
      }
  }

  const float bias_r  = bih[coln] + bhh[coln];
  const float bias_z  = bih[TN + coln] + bhh[TN + coln];
  const float bias_in = bih[2 * TN + coln];
  const float bias_hn = bhh[2 * TN + coln];

  float hstate[4] = {0.f, 0.f, 0.f, 0.f};
  int dead = 0;

  __syncthreads();

  const int bpat = mt * 16 + l4 * 4;

  for (int t = 0; t < TT; ++t) {
    const int st = dir ? (TT - 1 - t) : t;

    f32x4 acc_r  = {bias_r,  bias_r,  bias_r,  bias_r};
    f32x4 acc_z  = {bias_z,  bias_z,  bias_z,  bias_z};
    f32x4 acc_in = {bias_in, bias_in, bias_in, bias_in};
    f32x4 acc_hn = {bias_hn, bias_hn, bias_hn, bias_hn};

    const float* xr = x + (size_t)brow * (TT * TN) + (size_t)st * TN + l4 * 8;
    short8 af[16];
#pragma unroll
    for (int ks = 0; ks < 16; ++ks) af[ks] = pack_bf8(xr + ks * 32);
#pragma unroll
    for (int ks = 0; ks < 16; ++ks) {
      short8 b0 = *(const short8*)&wih_lds[nt][0][ks][lane * 8];
      acc_r = __builtin_amdgcn_mfma_f32_16x16x32_bf16(af[ks], b0, acc_r, 0, 0, 0);
      short8 b1 = *(const short8*)&wih_lds[nt][1][ks][lane * 8];
      acc_z = __builtin_amdgcn_mfma_f32_16x16x32_bf16(af[ks], b1, acc_z, 0, 0, 0);
      acc_in = __builtin_amdgcn_mfma_f32_16x16x32_bf16(af[ks], bwih_n[ks], acc_in, 0, 0, 0);
    }

    float xv[4];
#pragma unroll
    for (int r = 0; r < 4; ++r)
      xv[r] = x[(size_t)(bpat + r) * (TT * TN) + (size_t)st * TN + coln];

    if (t > 0 && !dead) {
      const unsigned target = (unsigned)t;
      int spins = 0;
      for (;;) {
        unsigned v = 0xFFFFFFFFu;
        if (lane < 16)
          v = __hip_atomic_load(&flg[lane], __ATOMIC_RELAXED, __HIP_MEMORY_SCOPE_AGENT);
        if (__ballot(v >= target) == ~0ull) break;
        if (++spins > (1 << 20)) { dead = 1; break; }
      }
      asm volatile("" ::: "memory");
    }

    const ull gb0 = (ull)(uintptr_t)hp + ((ull)(grp * 2 + ((t + 1) & 1)) << 14)
                  + (ull)((l4 >> 1) * 512 + l15 * 32 + (l4 & 1) * 16);
    const ull gb1 = gb0 + 4096, gb2 = gb0 + 8192, gb3 = gb0 + 12288;
    short8 hf[16];
    HLOAD(hf[0],  gb0, 0); HLOAD(hf[1],  gb0, 1024); HLOAD(hf[2],  gb0, 2048); HLOAD(hf[3],  gb0, 3072);
    HLOAD(hf[4],  gb1, 0); HLOAD(hf[5],  gb1, 1024); HLOAD(hf[6],  gb1, 2048); HLOAD(hf[7],  gb1, 3072);
    HLOAD(hf[8],  gb2, 0); HLOAD(hf[9],  gb2, 1024); HLOAD(hf[10], gb2, 2048); HLOAD(hf[11], gb2, 3072);
    HLOAD(hf[12], gb3, 0); HLOAD(hf[13], gb3, 1024); HLOAD(hf[14], gb3, 2048); HLOAD(hf[15], gb3, 3072);
    asm volatile("s_waitcnt vmcnt(0)" ::: "memory");
    __builtin_amdgcn_sched_barrier(0);

#pragma unroll
    for (int ks = 0; ks < 16; ++ks) {
      acc_r  = __builtin_amdgcn_mfma_f32_16x16x32_bf16(hf[ks], bwhh[0][ks], acc_r, 0, 0, 0);
      acc_z  = __builtin_amdgcn_mfma_f32_16x16x32_bf16(hf[ks], bwhh[1][ks], acc_z, 0, 0, 0);
      acc_hn = __builtin_amdgcn_mfma_f32_16x16x32_bf16(hf[ks], bwhh[2][ks], acc_hn, 0, 0, 0);
    }

    float hout[4];
#pragma unroll
    for (int r = 0; r < 4; ++r) {
      float rg = 1.0f / (1.0f + __expf(-acc_r[r]));
      float zg = 1.0f / (1.0f + __expf(-acc_z[r]));
      float e2 = __expf(2.0f * (acc_in[r] + rg * acc_hn[r]));
      float ng = 1.0f - 2.0f / (e2 + 1.0f);
      float hnew = (1.0f - zg) * ng + zg * hstate[r];
      hstate[r] = hnew;
      hout[r] = hnew;
    }

    {
      const int src0 = (lane & 48) + (lane & 3) * 4;
      float g0[4], g1[4], g2[4], g3[4];
#pragma unroll
      for (int k = 0; k < 4; ++k) {
        g0[k] = __shfl(hout[0], src0 + k, 64);
        g1[k] = __shfl(hout[1], src0 + k, 64);
        g2[k] = __shfl(hout[2], src0 + k, 64);
        g3[k] = __shfl(hout[3], src0 + k, 64);
      }
      const int rsel = (lane >> 2) & 3;
      float vv[4];
#pragma unroll
      for (int k = 0; k < 4; ++k) {
        float lo = (rsel & 1) ? g1[k] : g0[k];
        float hi = (rsel & 1) ? g3[k] : g2[k];
        vv[k] = (rsel & 2) ? hi : lo;
      }
      unsigned d0 = (unsigned)f2bf(vv[0]) | ((unsigned)f2bf(vv[1]) << 16);
      unsigned d1 = (unsigned)f2bf(vv[2]) | ((unsigned)f2bf(vv[3]) << 16);
      ull pk = (ull)d0 | ((ull)d1 << 32);
      ull* pw = (ull*)(hp + ((size_t)(grp * 2 + (t & 1)) << 14)
                          + (size_t)p * 512 + (size_t)lane * 8);
      __hip_atomic_store(pw, pk, __ATOMIC_RELAXED, __HIP_MEMORY_SCOPE_AGENT);
    }

    asm volatile("s_waitcnt vmcnt(0)" ::: "memory");
    __syncthreads();
    if (tid == 0)
      __hip_atomic_store(&flg[j], (unsigned)(t + 1), __ATOMIC_RELAXED,
                         __HIP_MEMORY_SCOPE_AGENT);

#pragma unroll
    for (int r = 0; r < 4; ++r) {
      __builtin_nontemporal_store(hout[r] + xv[r],
          out + (size_t)(bpat + r) * (TT * 2 * TN) + (size_t)t * (2 * TN) + dir * TN + coln);
    }
  }
}

// ---------------- launch ----------------
extern "C" void kernel_launch(void* const* d_in, const int* in_sizes, int n_in,
                              void* d_out, int out_size, void* d_ws, size_t ws_size,
                              hipStream_t stream) {
  const float* x    = (const float*)d_in[0];
  const float* WihF = (const float*)d_in[1];
  const float* WhhF = (const float*)d_in[2];
  const float* bihF = (const float*)d_in[3];
  const float* bhhF = (const float*)d_in[4];
  const float* WihB = (const float*)d_in[5];
  const float* WhhB = (const float*)d_in[6];
  const float* bihB = (const float*)d_in[7];
  const float* bhhB = (const float*)d_in[8];

  unsigned short* hbuf = (unsigned short*)d_ws;
  unsigned* flags      = (unsigned*)((char*)d_ws + (size_t)2 * 2 * TB * TN * 2);
  float* gi            = (float*)((char*)d_ws + GI_OFF);

  prep_kernel<<<64, 256, 0, stream>>>((short4v*)hbuf, flags);

  if (ws_size >= GI_OFF + GI_BYTES) {
    gi_kernel<<<512, 256, 0, stream>>>(x, WihF, WihB, bihF, bihB, gi);
    gru_kernel<<<32, 256, 0, stream>>>(x, WhhF, WhhB, bhhF, bhhB,
                                       gi, hbuf, flags, (float*)d_out);
  } else {
    gru_kernel_fb<<<32, 256, 0, stream>>>(
        x, WihF, WhhF, WihB, WhhB,
        bihF, bhhF, bihB, bhhB,
        hbuf, flags, (float*)d_out);
  }
}